// Round 10
// baseline (319.892 us; speedup 1.0000x reference)
//
#include <hip/hip_runtime.h>

// CausalSelfAttention: B=2, S=2048, D=1024, H=16, HD=64
#define B_  2
#define S_  2048
#define D_  1024
#define H_  16
#define HD_ 64
#define TD_ 3072
#define M_  (B_*S_)    // 4096
#define NWORK_ 40      // chunk-8 split-K items per plane (sizes <= 8 KV tiles)
#define PO_SPLIT_ 896  // items in pO region A (= exactly xb+wat = 14 MB)

using bf16x8 = __attribute__((ext_vector_type(8))) short;   // 8 bf16 = 4 VGPRs
using bf16x4 = __attribute__((ext_vector_type(4))) short;   // 4 bf16 = 2 VGPRs
using f32x4  = __attribute__((ext_vector_type(4))) float;   // MFMA C/D

typedef __attribute__((address_space(1))) unsigned int uint_g;
typedef __attribute__((address_space(3))) unsigned int uint_l;

#define MFMA32 __builtin_amdgcn_mfma_f32_16x16x32_bf16

// Device pass resolves one of these (R5/R8/R9 evidence: MFMA16 path taken on
// gfx950). Host pass sees neither -> parse-only stub.
#if defined(__has_builtin)
#if __has_builtin(__builtin_amdgcn_mfma_f32_16x16x16_bf16_1k)
#define MFMA16(a,b,c) __builtin_amdgcn_mfma_f32_16x16x16_bf16_1k(a,b,c,0,0,0)
#define HAVE_MFMA16 1
#elif __has_builtin(__builtin_amdgcn_mfma_f32_16x16x16bf16_1k)
#define MFMA16(a,b,c) __builtin_amdgcn_mfma_f32_16x16x16bf16_1k(a,b,c,0,0,0)
#define HAVE_MFMA16 1
#endif
#endif
#ifndef HAVE_MFMA16
static __device__ __forceinline__ f32x4 MFMA16_stub(bf16x4 a, bf16x4 b, f32x4 c) { return c; }
#define MFMA16(a,b,c) MFMA16_stub(a,b,c)   // parse-only (host pass)
#endif

static __device__ __forceinline__ short f2bf(float f) {
    unsigned u = __float_as_uint(f);
    u += 0x7FFFu + ((u >> 16) & 1u);   // round-to-nearest-even
    return (short)(u >> 16);
}
static __device__ __forceinline__ unsigned pack2bf(float a, float b) {
    return (unsigned)(unsigned short)f2bf(a) | ((unsigned)(unsigned short)f2bf(b) << 16);
}
// async global->LDS, 16B/lane; LDS dest = uniform base + lane*16 (m97/m104 semantics)
static __device__ __forceinline__ void gload_lds16(const short* g, short* l) {
    __builtin_amdgcn_global_load_lds((const uint_g*)g, (uint_l*)l, 16, 0, 0);
}
// unpack 8 bf16 (uint4) -> 8 floats
static __device__ __forceinline__ void unpack8(uint4 u, float* f) {
    unsigned a0 = u.x, a1 = u.y, a2 = u.z, a3 = u.w;
    f[0] = __uint_as_float(a0 << 16); f[1] = __uint_as_float(a0 & 0xFFFF0000u);
    f[2] = __uint_as_float(a1 << 16); f[3] = __uint_as_float(a1 & 0xFFFF0000u);
    f[4] = __uint_as_float(a2 << 16); f[5] = __uint_as_float(a2 & 0xFFFF0000u);
    f[6] = __uint_as_float(a3 << 16); f[7] = __uint_as_float(a3 & 0xFFFF0000u);
}
// split-region pO addressing: item < PO_SPLIT_ in region A (dead xb+wat),
// else region B (dead vg). 16 KB (8192 shorts) per item.
static __device__ __forceinline__ const short* pO_ptr_c(const short* A, const short* B, int item) {
    return (item < PO_SPLIT_) ? A + (size_t)item * 8192 : B + (size_t)(item - PO_SPLIT_) * 8192;
}
static __device__ __forceinline__ short* pO_ptr(short* A, short* B, int item) {
    return (item < PO_SPLIT_) ? A + (size_t)item * 8192 : B + (size_t)(item - PO_SPLIT_) * 8192;
}

// ---------------------------------------------------------------------------
// Fused prep: blocks [0,4096) cast x->bf16; [4096,7168) transpose w_attn;
// [7168,8192) transpose w_proj. One launch instead of three.
// ---------------------------------------------------------------------------
__global__ __launch_bounds__(256)
void prep_kernel(const float* __restrict__ x, short* __restrict__ xb,
                 const float* __restrict__ w_attn, short* __restrict__ wat,
                 const float* __restrict__ w_proj, short* __restrict__ wpt) {
    __shared__ float T[32][33];
    const int id  = blockIdx.x;
    const int tid = threadIdx.x;
    if (id < 4096) {
        int i = id * 256 + tid;
        float4 v = *((const float4*)x + i);
        short4 o;
        o.x = f2bf(v.x); o.y = f2bf(v.y); o.z = f2bf(v.z); o.w = f2bf(v.w);
        *((short4*)xb + i) = o;
        return;
    }
    const float* W; short* Wt; int K, N, n0, k0;
    if (id < 7168) {
        int i = id - 4096; W = w_attn; Wt = wat; K = D_; N = TD_;
        n0 = (i % 96) * 32; k0 = (i / 96) * 32;
    } else {
        int i = id - 7168; W = w_proj; Wt = wpt; K = D_; N = D_;
        n0 = (i & 31) * 32; k0 = (i >> 5) * 32;
    }
    int tx = tid & 31, ty = tid >> 5;
    #pragma unroll
    for (int i = 0; i < 4; ++i)
        T[ty + i * 8][tx] = W[(size_t)(k0 + ty + i * 8) * N + n0 + tx];
    __syncthreads();
    #pragma unroll
    for (int i = 0; i < 4; ++i)
        Wt[(size_t)(n0 + ty + i * 8) * K + k0 + tx] = f2bf(T[tx][ty + i * 8]);
}

// ---------------------------------------------------------------------------
// V [B,H,S,HD] bf16 -> Vt [B,H,HD,S] bf16
// ---------------------------------------------------------------------------
__global__ __launch_bounds__(256)
void vtrans_kernel(const short* __restrict__ V, short* __restrict__ Vt) {
    __shared__ short T[32][33];
    int p  = blockIdx.z;
    int s0 = blockIdx.x * 32;
    int d0 = blockIdx.y * 32;
    int tx = threadIdx.x & 31, ty = threadIdx.x >> 5;
    const short* Vp  = V  + (size_t)p * S_ * HD_;
    short*       Vtp = Vt + (size_t)p * HD_ * S_;
    #pragma unroll
    for (int i = 0; i < 4; ++i)
        T[ty + i * 8][tx] = Vp[(s0 + ty + i * 8) * HD_ + d0 + tx];
    __syncthreads();
    #pragma unroll
    for (int i = 0; i < 4; ++i)
        Vtp[(size_t)(d0 + ty + i * 8) * S_ + s0 + tx] = T[tx][ty + i * 8];
}

// ---------------------------------------------------------------------------
// QKV GEMM, m97 structure: 128x128 tile, BK=32, global_load_lds w=16.
// Epilogue scatters Q(scaled)/K/V bf16 to [B,H,S,HD].
// ---------------------------------------------------------------------------
__global__ __launch_bounds__(256)
void qkv_gemm_kernel(const short* __restrict__ A, const short* __restrict__ Bt,
                     const float* __restrict__ bias,
                     short* __restrict__ Qo, short* __restrict__ Ko, short* __restrict__ Vo) {
    __shared__ __align__(16) short As[128 * 32];
    __shared__ __align__(16) short Bs[128 * 32];

    const int tid  = threadIdx.x;
    const int w    = tid >> 6, lane = tid & 63;
    const int quad = lane >> 4, l16 = lane & 15;
    const int wr = (w >> 1) * 64, wc = (w & 1) * 64;
    const int rowBase = blockIdx.y * 128, colBase = blockIdx.x * 128;
    const int K = D_;

    f32x4 acc[4][4];
    const f32x4 zero = {0.f, 0.f, 0.f, 0.f};
    #pragma unroll
    for (int i = 0; i < 4; ++i)
        #pragma unroll
        for (int j = 0; j < 4; ++j) acc[i][j] = zero;

    const int srow = lane >> 2;
    const int scol = (lane & 3) * 8;

    for (int k0 = 0; k0 < K; k0 += 32) {
        __syncthreads();
        gload_lds16(A  + (size_t)(rowBase + w * 16 + srow)      * K + k0 + scol, &As[(w * 16) * 32]);
        gload_lds16(A  + (size_t)(rowBase + 64 + w * 16 + srow) * K + k0 + scol, &As[(64 + w * 16) * 32]);
        gload_lds16(Bt + (size_t)(colBase + w * 16 + srow)      * K + k0 + scol, &Bs[(w * 16) * 32]);
        gload_lds16(Bt + (size_t)(colBase + 64 + w * 16 + srow) * K + k0 + scol, &Bs[(64 + w * 16) * 32]);
        __syncthreads();

        bf16x8 af[4], bf[4];
        #pragma unroll
        for (int t = 0; t < 4; ++t) {
            af[t] = *(const bf16x8*)&As[(wr + t * 16 + l16) * 32 + quad * 8];
            bf[t] = *(const bf16x8*)&Bs[(wc + t * 16 + l16) * 32 + quad * 8];
        }
        #pragma unroll
        for (int i = 0; i < 4; ++i)
            #pragma unroll
            for (int j = 0; j < 4; ++j)
                acc[i][j] = MFMA32(af[i], bf[j], acc[i][j], 0, 0, 0);
    }

    #pragma unroll
    for (int j = 0; j < 4; ++j) {
        int col = colBase + wc + j * 16 + l16;
        int sel = col >> 10, cr = col & 1023;
        int h = cr >> 6, d = cr & 63;
        float bv  = bias[col];
        short* dst = (sel == 0) ? Qo : (sel == 1) ? Ko : Vo;
        float  scl = (sel == 0) ? 0.125f : 1.0f;   // softmax scale folded into Q
        #pragma unroll
        for (int i = 0; i < 4; ++i) {
            int row = rowBase + wr + i * 16 + quad * 4;
            #pragma unroll
            for (int r = 0; r < 4; ++r) {
                int rw = row + r;
                int bb = rw >> 11, s = rw & 2047;
                dst[((size_t)(bb * H_ + h) * S_ + s) * HD_ + d] =
                    f2bf((acc[i][j][r] + bv) * scl);
            }
        }
    }
}

// ---------------------------------------------------------------------------
// Split-K flash attention v10: uniform chunks of <= 8 KV tiles.
// 256 thr / 4 waves, BQ=128, 32 q rows per wave (two 16-row subtiles).
// Item y in [0,40): qi has ceil((2qi+2)/8) chunks; group g=qi>>2 has g+1
// chunks per qi, group base 2g(g+1). 1280 blocks (~5/CU, all co-resident,
// sizes <= 8 iters -> bounded tail). Unnormalized partials (no-max softmax):
// pO split across two dead ws regions, pl fp32.
// ---------------------------------------------------------------------------
__global__ __launch_bounds__(256, 6)
void flash_mfma_kernel(const short* __restrict__ Qg, const short* __restrict__ Kg,
                       const short* __restrict__ Vtg,
                       short* __restrict__ poA, short* __restrict__ poB,
                       float* __restrict__ pl) {
    __shared__ __align__(16) short Ks[64][72];
    __shared__ __align__(16) short Vs[64][72];   // Vs[d][kv]

    const int plane_id = blockIdx.x;                       // b*H + h
    const int y = (int)(gridDim.y - 1) - (int)blockIdx.y;  // heavy chunks first
    const int g = (y < 4) ? 0 : (y < 12) ? 1 : (y < 24) ? 2 : 3;
    const int rem = y - 2 * g * (g + 1);
    const int qi = 4 * g + rem / (g + 1);
    const int kc = rem - (rem / (g + 1)) * (g + 1);
    int nkt = 2 * qi + 2 - kc * 8;
    if (nkt > 8) nkt = 8;
    const int kvOrigin = kc * 512;
    const int item = plane_id * NWORK_ + y;

    const int tid  = threadIdx.x;
    const int w    = tid >> 6, lane = tid & 63;
    const int quad = lane >> 4, l16 = lane & 15;
    const int qBase = qi * 128;
    const size_t plane = (size_t)plane_id * S_ * HD_;

    // staging: thread covers rows sr0 and sr0+32, cols sc0..sc0+7 (shorts)
    const int sr0 = tid >> 3;          // 0..31
    const int sc0 = (tid & 7) * 8;

    // Q B-frags for both subtiles (already 1/8-scaled at GEMM1 epilogue)
    const int qsubA = qBase + w * 32;
    const short* QrowA = Qg + plane + (size_t)(qsubA + l16) * HD_ + quad * 8;
    const bf16x8 qa0 = *(const bf16x8*)(QrowA);
    const bf16x8 qa1 = *(const bf16x8*)(QrowA + 32);
    const short* QrowB = QrowA + 16 * HD_;
    const bf16x8 qb0 = *(const bf16x8*)(QrowB);
    const bf16x8 qb1 = *(const bf16x8*)(QrowB + 32);

    f32x4 oA[4], oB[4];
    const f32x4 zero = {0.f, 0.f, 0.f, 0.f};
    #pragma unroll
    for (int i = 0; i < 4; ++i) { oA[i] = zero; oB[i] = zero; }
    float lA = 0.f, lB = 0.f;
    const int q_globA = qsubA + l16;
    const int q_globB = qsubA + 16 + l16;
    const int q_wave_max = qsubA + 31;

    // prefetch tile j=0
    uint4 ka0, ka1, va0, va1;
    ka0 = *(const uint4*)(Kg  + plane + (size_t)(kvOrigin + sr0)      * HD_ + sc0);
    ka1 = *(const uint4*)(Kg  + plane + (size_t)(kvOrigin + sr0 + 32) * HD_ + sc0);
    va0 = *(const uint4*)(Vtg + plane + (size_t)sr0        * S_ + kvOrigin + sc0);
    va1 = *(const uint4*)(Vtg + plane + (size_t)(sr0 + 32) * S_ + kvOrigin + sc0);

    for (int j = 0; j < nkt; ++j) {
        __syncthreads();                   // prev iter's LDS reads done
        *(uint4*)&Ks[sr0][sc0]      = ka0; // implicit vmcnt wait
        *(uint4*)&Ks[sr0 + 32][sc0] = ka1;
        *(uint4*)&Vs[sr0][sc0]      = va0;
        *(uint4*)&Vs[sr0 + 32][sc0] = va1;
        __syncthreads();                   // tile visible to all waves

        if (j + 1 < nkt) {                 // issue next-tile loads now
            const int kvB = kvOrigin + (j + 1) * 64;
            ka0 = *(const uint4*)(Kg  + plane + (size_t)(kvB + sr0)      * HD_ + sc0);
            ka1 = *(const uint4*)(Kg  + plane + (size_t)(kvB + sr0 + 32) * HD_ + sc0);
            va0 = *(const uint4*)(Vtg + plane + (size_t)sr0        * S_ + kvB + sc0);
            va1 = *(const uint4*)(Vtg + plane + (size_t)(sr0 + 32) * S_ + kvB + sc0);
        }

        const int kvBase = kvOrigin + j * 64;
        if (kvBase > q_wave_max) continue;     // wave entirely above diagonal

        // ---- S^T = K Q^T for BOTH subtiles: each kf read feeds 2 MFMAs
        f32x4 sA[4], sB[4];
        #pragma unroll
        for (int ct = 0; ct < 4; ++ct) {
            bf16x8 kf0 = *(const bf16x8*)&Ks[ct * 16 + l16][quad * 8];
            bf16x8 kf1 = *(const bf16x8*)&Ks[ct * 16 + l16][32 + quad * 8];
            f32x4 a = zero, b = zero;
            a = MFMA32(kf0, qa0, a, 0, 0, 0);
            a = MFMA32(kf1, qa1, a, 0, 0, 0);
            b = MFMA32(kf0, qb0, b, 0, 0, 0);
            b = MFMA32(kf1, qb1, b, 0, 0, 0);
            sA[ct] = a; sB[ct] = b;
        }

        // ---- causal mask per subtile (only near the diagonal)
        if (kvBase + 63 > qsubA) {
            #pragma unroll
            for (int ct = 0; ct < 4; ++ct) {
                int kv = kvBase + ct * 16 + quad * 4;
                #pragma unroll
                for (int r = 0; r < 4; ++r)
                    if (kv + r > q_globA) sA[ct][r] = -3.0e38f;
            }
        }
        if (kvBase + 63 > qsubA + 16) {
            #pragma unroll
            for (int ct = 0; ct < 4; ++ct) {
                int kv = kvBase + ct * 16 + quad * 4;
                #pragma unroll
                for (int r = 0; r < 4; ++r)
                    if (kv + r > q_globB) sB[ct][r] = -3.0e38f;
            }
        }

        // ---- no-max softmax + PV: each vfr read feeds 2 MFMA16s
        #pragma unroll
        for (int ct = 0; ct < 4; ++ct) {
            float pa0 = __expf(sA[ct][0]), pa1 = __expf(sA[ct][1]);
            float pa2 = __expf(sA[ct][2]), pa3 = __expf(sA[ct][3]);
            float pb0 = __expf(sB[ct][0]), pb1 = __expf(sB[ct][1]);
            float pb2 = __expf(sB[ct][2]), pb3 = __expf(sB[ct][3]);
            lA += (pa0 + pa1) + (pa2 + pa3);
            lB += (pb0 + pb1) + (pb2 + pb3);
            bf16x4 pA, pB;
            *(unsigned*)&pA       = pack2bf(pa0, pa1);
            *((unsigned*)&pA + 1) = pack2bf(pa2, pa3);
            *(unsigned*)&pB       = pack2bf(pb0, pb1);
            *((unsigned*)&pB + 1) = pack2bf(pb2, pb3);
            #pragma unroll
            for (int dt = 0; dt < 4; ++dt) {
                bf16x4 vfr = *(const bf16x4*)&Vs[dt * 16 + l16][ct * 16 + quad * 4];
                oA[dt] = MFMA16(vfr, pA, oA[dt]);
                oB[dt] = MFMA16(vfr, pB, oB[dt]);
            }
        }
    }

    // ---- l partials: reduce over quads, store per q row
    lA += __shfl_xor(lA, 16); lA += __shfl_xor(lA, 32);
    lB += __shfl_xor(lB, 16); lB += __shfl_xor(lB, 32);
    const size_t lbase = (size_t)item * 128 + w * 32;
    if (quad == 0) {
        pl[lbase + l16]      = lA;
        pl[lbase + 16 + l16] = lB;
    }

    // ---- O partials: transpose via LDS (reuse Ks/Vs), b128 coalesced store
    __syncthreads();                       // all K/V readers done before reuse
    short* Pw = (w < 2) ? &Ks[w * 32][0] : &Vs[(w - 2) * 32][0];
    #pragma unroll
    for (int dt = 0; dt < 4; ++dt) {
        uint2 ua, ub;
        ua.x = pack2bf(oA[dt][0], oA[dt][1]);
        ua.y = pack2bf(oA[dt][2], oA[dt][3]);
        ub.x = pack2bf(oB[dt][0], oB[dt][1]);
        ub.y = pack2bf(oB[dt][2], oB[dt][3]);
        *(uint2*)&Pw[l16 * 72 + dt * 16 + quad * 4]        = ua;  // [q_loc][d]
        *(uint2*)&Pw[(16 + l16) * 72 + dt * 16 + quad * 4] = ub;
    }
    __builtin_amdgcn_s_waitcnt(0xC07F);    // lgkmcnt(0): own-wave writes done
    short* outBase = pO_ptr(poA, poB, item) + (size_t)(w * 32) * 64;
    #pragma unroll
    for (int pass = 0; pass < 4; ++pass) {
        int r  = pass * 8 + (lane >> 3);   // 0..31
        int cs = (lane & 7) * 8;
        uint4 vv = *(const uint4*)&Pw[r * 72 + cs];
        *(uint4*)(outBase + r * 64 + cs) = vv;
    }
}

// ---------------------------------------------------------------------------
// Reduce split-K partials: atb[q][h*64+d] = (sum_ch O_part) / (sum_ch l_part)
// Grid (32 planes, 16 qi), 256 threads; thread owns 1 row x 32 cols.
// qi -> first item t0 = 2g(g+1) + (qi-4g)(g+1), nch = g+1 (g = qi>>2).
// ---------------------------------------------------------------------------
__global__ __launch_bounds__(256)
void reduce_kernel(const short* __restrict__ poA, const short* __restrict__ poB,
                   const float* __restrict__ pl, short* __restrict__ atb) {
    const int plane_id = blockIdx.x, qi = blockIdx.y;
    const int h = plane_id & (H_ - 1), b = plane_id >> 4;
    const int tid = threadIdx.x;
    const int row = tid >> 1;              // 0..127
    const int cb  = (tid & 1) * 32;        // 0 or 32

    const int g = qi >> 2;
    const int t0 = 2 * g * (g + 1) + (qi - 4 * g) * (g + 1);
    const int nch = g + 1;
    const int item0 = plane_id * NWORK_ + t0;

    float f[32];
    #pragma unroll
    for (int i = 0; i < 32; ++i) f[i] = 0.f;
    float l = 0.f;
    for (int ch = 0; ch < nch; ++ch) {
        const short* p = pO_ptr_c(poA, poB, item0 + ch) + (size_t)row * 64 + cb;
        float g8[8];
        #pragma unroll
        for (int c = 0; c < 4; ++c) {
            unpack8(*(const uint4*)(p + c * 8), g8);
            #pragma unroll
            for (int i = 0; i < 8; ++i) f[c * 8 + i] += g8[i];
        }
        l += pl[(size_t)(item0 + ch) * 128 + row];
    }
    const float inv = 1.0f / l;
    short* dst = atb + (size_t)(b * S_ + qi * 128 + row) * D_ + h * HD_ + cb;
    #pragma unroll
    for (int c = 0; c < 4; ++c) {
        uint4 ov;
        ov.x = pack2bf(f[c * 8 + 0] * inv, f[c * 8 + 1] * inv);
        ov.y = pack2bf(f[c * 8 + 2] * inv, f[c * 8 + 3] * inv);
        ov.z = pack2bf(f[c * 8 + 4] * inv, f[c * 8 + 5] * inv);
        ov.w = pack2bf(f[c * 8 + 6] * inv, f[c * 8 + 7] * inv);
        *(uint4*)(dst + c * 8) = ov;
    }
}

// ---------------------------------------------------------------------------
// Output projection GEMM: 64x128 tile (512 blocks = 2/CU vs 1/CU at 128x128).
// Block 256 thr / 4 waves in 1x4; wave w covers cols [w*32, w*32+32).
// C fp32 + bias. A = atb [M][1024] bf16, Bt = wpt [1024][1024] bf16.
// ---------------------------------------------------------------------------
__global__ __launch_bounds__(256)
void gemm2_mfma_kernel(const short* __restrict__ A, const short* __restrict__ Bt,
                       const float* __restrict__ bias, float* __restrict__ Cf) {
    __shared__ __align__(16) short As[64 * 32];
    __shared__ __align__(16) short Bs[128 * 32];

    const int tid  = threadIdx.x;
    const int w    = tid >> 6, lane = tid & 63;
    const int quad = lane >> 4, l16 = lane & 15;
    const int rowBase = blockIdx.y * 64, colBase = blockIdx.x * 128;
    const int K = D_;

    f32x4 acc[4][2];
    const f32x4 zero = {0.f, 0.f, 0.f, 0.f};
    #pragma unroll
    for (int i = 0; i < 4; ++i) { acc[i][0] = zero; acc[i][1] = zero; }

    const int srow = lane >> 2;
    const int scol = (lane & 3) * 8;

    for (int k0 = 0; k0 < K; k0 += 32) {
        __syncthreads();
        gload_lds16(A  + (size_t)(rowBase + w * 16 + srow)      * K + k0 + scol, &As[(w * 16) * 32]);
        gload_lds16(Bt + (size_t)(colBase + w * 16 + srow)      * K + k0 + scol, &Bs[(w * 16) * 32]);
        gload_lds16(Bt + (size_t)(colBase + 64 + w * 16 + srow) * K + k0 + scol, &Bs[(64 + w * 16) * 32]);
        __syncthreads();

        bf16x8 af[4], bf[2];
        #pragma unroll
        for (int t = 0; t < 4; ++t)
            af[t] = *(const bf16x8*)&As[(t * 16 + l16) * 32 + quad * 8];
        #pragma unroll
        for (int t = 0; t < 2; ++t)
            bf[t] = *(const bf16x8*)&Bs[(w * 32 + t * 16 + l16) * 32 + quad * 8];
        #pragma unroll
        for (int i = 0; i < 4; ++i)
            #pragma unroll
            for (int j = 0; j < 2; ++j)
                acc[i][j] = MFMA32(af[i], bf[j], acc[i][j], 0, 0, 0);
    }

    #pragma unroll
    for (int i = 0; i < 4; ++i) {
        int row = rowBase + i * 16 + quad * 4;
        #pragma unroll
        for (int j = 0; j < 2; ++j) {
            int col = colBase + w * 32 + j * 16 + l16;
            float bv = bias[col];
            #pragma unroll
            for (int r = 0; r < 4; ++r)
                Cf[(size_t)(row + r) * D_ + col] = acc[i][j][r] + bv;
        }
    }
}

// ---------------------------------------------------------------------------
extern "C" void kernel_launch(void* const* d_in, const int* in_sizes, int n_in,
                              void* d_out, int out_size, void* d_ws, size_t ws_size,
                              hipStream_t stream) {
    const float* x      = (const float*)d_in[0];
    const float* w_attn = (const float*)d_in[1];
    const float* b_attn = (const float*)d_in[2];
    const float* w_proj = (const float*)d_in[3];
    const float* b_proj = (const float*)d_in[4];
    float* out = (float*)d_out;

    // Layout (56 MB used, pl extends to 56.63 MB; ws known >= 64 MB from R1):
    // [wpt 2][xb 8][wat 6][qg 8][kg 8][vtg 8][atb 8][vg 8] | pl
    // pO region A = xb+wat (14 MB = exactly 896 items); region B = vg (dead
    // after vtrans; 384 items = 6.29 MB <= 8 MB).
    char* ws = (char*)d_ws;
    short* wpt = (short*)ws; ws += (size_t)D_ * D_ * 2;    // 2 MB
    short* xb  = (short*)ws; ws += (size_t)M_ * D_ * 2;    // 8 MB (dead after gemm1)
    short* wat = (short*)ws; ws += (size_t)TD_ * D_ * 2;   // 6 MB (dead after gemm1)
    short* qg  = (short*)ws; ws += (size_t)M_ * D_ * 2;    // 8 MB
    short* kg  = (short*)ws; ws += (size_t)M_ * D_ * 2;    // 8 MB
    short* vtg = (short*)ws; ws += (size_t)M_ * D_ * 2;    // 8 MB
    short* atb = (short*)ws; ws += (size_t)M_ * D_ * 2;    // 8 MB
    short* vg  = (short*)ws; ws += (size_t)M_ * D_ * 2;    // 8 MB (dead after vtrans)

    short* poA = xb;                                       // 14 MB contiguous
    short* poB = vg;                                       // 6.29 MB used
    float* pl  = (float*)ws;                               // 0.66 MB @ 56 MB

    // 1) fused prep: cast x + transpose both weights (one launch)
    prep_kernel<<<8192, 256, 0, stream>>>(x, xb, w_attn, wat, w_proj, wpt);

    // 2) QKV projection -> q (scaled) / k / v bf16 [B,H,S,HD]
    qkv_gemm_kernel<<<dim3(TD_ / 128, M_ / 128), 256, 0, stream>>>(
        xb, wat, b_attn, qg, kg, vg);

    // 3) V -> V^T [B,H,HD,S]
    vtrans_kernel<<<dim3(S_ / 32, HD_ / 32, B_ * H_), 256, 0, stream>>>(vg, vtg);

    // 4) split-K flash (uniform <=8-tile chunks); plane fastest for XCD L2 reuse
    flash_mfma_kernel<<<dim3(B_ * H_, NWORK_), 256, 0, stream>>>(
        qg, kg, vtg, poA, poB, pl);

    // 5) combine partials -> atb bf16 [B*S][D]
    reduce_kernel<<<dim3(B_ * H_, S_ / 128), 256, 0, stream>>>(poA, poB, pl, atb);

    // 6) output projection -> fp32 out
    gemm2_mfma_kernel<<<dim3(D_ / 128, M_ / 64), 256, 0, stream>>>(
        atb, wpt, b_proj, out);
}